// Round 1
// baseline (45.963 us; speedup 1.0000x reference)
//
#include <hip/hip_runtime.h>

#define N_NUM 64
#define N_CAT 32
#define CAT_W 8
#define N_ICD 128
#define BATCH 131072

// W layout (2 x 448): [0:64)=num, [64:320)=cat (32x8), [320:448)=icd
// M layout (2 x 224): [0:64)=num, [64:96)=cat,         [96:224)=icd
#define WROW 448
#define MROW 224

__device__ __forceinline__ float fast_tanh(float x) {
    // tanh(x) = 1 - 2/(exp(2x)+1); native exp & rcp saturate correctly at +-inf
    float e = __expf(2.0f * x);
    return 1.0f - 2.0f * __builtin_amdgcn_rcpf(e + 1.0f);
}

__global__ void __launch_bounds__(256)
phenotype_softmax_kernel(const float* __restrict__ num_x,
                         const float* __restrict__ cat_x,
                         const float* __restrict__ icd_x,
                         const float* __restrict__ W,
                         const float* __restrict__ M,
                         float* __restrict__ out) {
    __shared__ float4 sNum[N_NUM];        // {W0, W1, M0, M1}
    __shared__ float4 sIcd[N_ICD];        // {W0, W1, M0, M1}
    __shared__ float4 sCatW[N_CAT][4];    // per g: {W0[w],W1[w],W0[w+1],W1[w+1]} w=0,2,4,6
    __shared__ float2 sCatM[N_CAT];       // {M0, M1}

    const int t = threadIdx.x;

    if (t < N_NUM) {
        sNum[t] = make_float4(W[t], W[WROW + t], M[t], M[MROW + t]);
    }
    if (t < N_ICD) {
        sIcd[t] = make_float4(W[320 + t], W[WROW + 320 + t],
                              M[96 + t],  M[MROW + 96 + t]);
    }
    if (t < N_CAT * 4) {  // 128 threads: g = t/4, quad q covers w=2q,2q+1
        int g = t >> 2, q = t & 3, w = 2 * q;
        int base = 64 + g * 8 + w;
        sCatW[g][q] = make_float4(W[base],     W[WROW + base],
                                  W[base + 1], W[WROW + base + 1]);
    }
    if (t < N_CAT) {
        sCatM[t] = make_float2(M[64 + t], M[MROW + 64 + t]);
    }
    __syncthreads();

    const int b = blockIdx.x * 256 + t;
    if (b >= BATCH) return;

    float f0 = 0.0f, f1 = 0.0f;

    // ---- numerical: 64 features, coalesced dword loads ----
#pragma unroll 16
    for (int n = 0; n < N_NUM; ++n) {
        float x = num_x[n * BATCH + b];
        float4 c = sNum[n];
        f0 = fmaf(c.z, fast_tanh(c.x * x), f0);
        f1 = fmaf(c.w, fast_tanh(c.y * x), f1);
    }

    // ---- categorical: 32 groups x 8-wide dot, 2x float4 per group ----
#pragma unroll 4
    for (int g = 0; g < N_CAT; ++g) {
        const float4* vp = reinterpret_cast<const float4*>(cat_x + ((size_t)g * BATCH + b) * CAT_W);
        float4 v0 = vp[0];
        float4 v1 = vp[1];
        float4 p0 = sCatW[g][0];
        float4 p1 = sCatW[g][1];
        float4 p2 = sCatW[g][2];
        float4 p3 = sCatW[g][3];
        float s0, s1;
        s0 = v0.x * p0.x;            s1 = v0.x * p0.y;
        s0 = fmaf(v0.y, p0.z, s0);   s1 = fmaf(v0.y, p0.w, s1);
        s0 = fmaf(v0.z, p1.x, s0);   s1 = fmaf(v0.z, p1.y, s1);
        s0 = fmaf(v0.w, p1.z, s0);   s1 = fmaf(v0.w, p1.w, s1);
        s0 = fmaf(v1.x, p2.x, s0);   s1 = fmaf(v1.x, p2.y, s1);
        s0 = fmaf(v1.y, p2.z, s0);   s1 = fmaf(v1.y, p2.w, s1);
        s0 = fmaf(v1.z, p3.x, s0);   s1 = fmaf(v1.z, p3.y, s1);
        s0 = fmaf(v1.w, p3.z, s0);   s1 = fmaf(v1.w, p3.w, s1);
        float2 m = sCatM[g];
        f0 = fmaf(m.x, fast_tanh(s0), f0);
        f1 = fmaf(m.y, fast_tanh(s1), f1);
    }

    // ---- icd: 128 features, coalesced dword loads ----
#pragma unroll 16
    for (int n = 0; n < N_ICD; ++n) {
        float x = icd_x[n * BATCH + b];
        float4 c = sIcd[n];
        f0 = fmaf(c.z, fast_tanh(c.x * x), f0);
        f1 = fmaf(c.w, fast_tanh(c.y * x), f1);
    }

    // ---- 2-class softmax: sigmoid of the logit difference ----
    float d = f0 - f1;
    float e0 = __expf(-d);   // exp(f1 - f0)
    float e1 = __expf(d);    // exp(f0 - f1)
    out[b]         = __builtin_amdgcn_rcpf(1.0f + e0);
    out[BATCH + b] = __builtin_amdgcn_rcpf(1.0f + e1);
}

extern "C" void kernel_launch(void* const* d_in, const int* in_sizes, int n_in,
                              void* d_out, int out_size, void* d_ws, size_t ws_size,
                              hipStream_t stream) {
    const float* num_x = (const float*)d_in[0];
    const float* cat_x = (const float*)d_in[1];
    const float* icd_x = (const float*)d_in[2];
    const float* W     = (const float*)d_in[3];
    const float* M     = (const float*)d_in[4];
    float* out = (float*)d_out;

    dim3 block(256);
    dim3 grid((BATCH + 255) / 256);  // 512 blocks
    phenotype_softmax_kernel<<<grid, block, 0, stream>>>(num_x, cat_x, icd_x, W, M, out);
}

// Round 2
// 44.669 us; speedup vs baseline: 1.0290x; 1.0290x over previous
//
#include <hip/hip_runtime.h>

#define N_NUM 64
#define N_CAT 32
#define CAT_W 8
#define N_ICD 128
#define BATCH 131072

// W layout (2 x 448): [0:64)=num, [64:320)=cat (32x8), [320:448)=icd
// M layout (2 x 224): [0:64)=num, [64:96)=cat,         [96:224)=icd
#define WROW 448
#define MROW 224

__device__ __forceinline__ float fast_tanh(float x) {
    // tanh(x) = 1 - 2/(exp(2x)+1); native exp & rcp saturate correctly at +-inf
    float e = __expf(2.0f * x);
    return 1.0f - 2.0f * __builtin_amdgcn_rcpf(e + 1.0f);
}

// 4 waves per block; wave w handles feature-quarter w for 64 batch elems.
// Per-thread bytes: num 16*4 + cat 8*32 + icd 32*4 = 448 B (balanced).
__global__ void __launch_bounds__(256, 8)
phenotype_softmax_kernel(const float* __restrict__ num_x,
                         const float* __restrict__ cat_x,
                         const float* __restrict__ icd_x,
                         const float* __restrict__ W,
                         const float* __restrict__ M,
                         float* __restrict__ out) {
    __shared__ float4 sNum[N_NUM];        // {W0, W1, M0, M1}
    __shared__ float4 sIcd[N_ICD];        // {W0, W1, M0, M1}
    __shared__ float4 sCatW[N_CAT][4];    // per g: {W0[w],W1[w],W0[w+1],W1[w+1]} w=0,2,4,6
    __shared__ float2 sCatM[N_CAT];       // {M0, M1}
    __shared__ float2 sPart[4][64];       // per-wave partial (f0,f1) per batch elem

    const int t = threadIdx.x;

    if (t < N_NUM) {
        sNum[t] = make_float4(W[t], W[WROW + t], M[t], M[MROW + t]);
    }
    if (t < N_ICD) {
        sIcd[t] = make_float4(W[320 + t], W[WROW + 320 + t],
                              M[96 + t],  M[MROW + 96 + t]);
    }
    if (t < N_CAT * 4) {  // 128 threads: g = t/4, quad q covers w=2q,2q+1
        int g = t >> 2, q = t & 3, w = 2 * q;
        int base = 64 + g * 8 + w;
        sCatW[g][q] = make_float4(W[base],     W[WROW + base],
                                  W[base + 1], W[WROW + base + 1]);
    }
    if (t < N_CAT) {
        sCatM[t] = make_float2(M[64 + t], M[MROW + 64 + t]);
    }
    __syncthreads();

    const int wave = t >> 6;
    const int lane = t & 63;
    const int b    = blockIdx.x * 64 + lane;

    float f0 = 0.0f, f1 = 0.0f;

    // ---- numerical: 16 features for this wave ----
    const int n0 = wave * 16;
#pragma unroll
    for (int i = 0; i < 16; ++i) {
        int n = n0 + i;
        float x = num_x[(size_t)n * BATCH + b];
        float4 c = sNum[n];
        f0 = fmaf(c.z, fast_tanh(c.x * x), f0);
        f1 = fmaf(c.w, fast_tanh(c.y * x), f1);
    }

    // ---- categorical: 8 groups for this wave, 2x float4 per group ----
    const int g0 = wave * 8;
#pragma unroll
    for (int i = 0; i < 8; ++i) {
        int g = g0 + i;
        const float4* vp = reinterpret_cast<const float4*>(cat_x + ((size_t)g * BATCH + b) * CAT_W);
        float4 v0 = vp[0];
        float4 v1 = vp[1];
        float4 p0 = sCatW[g][0];
        float4 p1 = sCatW[g][1];
        float4 p2 = sCatW[g][2];
        float4 p3 = sCatW[g][3];
        float s0, s1;
        s0 = v0.x * p0.x;            s1 = v0.x * p0.y;
        s0 = fmaf(v0.y, p0.z, s0);   s1 = fmaf(v0.y, p0.w, s1);
        s0 = fmaf(v0.z, p1.x, s0);   s1 = fmaf(v0.z, p1.y, s1);
        s0 = fmaf(v0.w, p1.z, s0);   s1 = fmaf(v0.w, p1.w, s1);
        s0 = fmaf(v1.x, p2.x, s0);   s1 = fmaf(v1.x, p2.y, s1);
        s0 = fmaf(v1.y, p2.z, s0);   s1 = fmaf(v1.y, p2.w, s1);
        s0 = fmaf(v1.z, p3.x, s0);   s1 = fmaf(v1.z, p3.y, s1);
        s0 = fmaf(v1.w, p3.z, s0);   s1 = fmaf(v1.w, p3.w, s1);
        float2 m = sCatM[g];
        f0 = fmaf(m.x, fast_tanh(s0), f0);
        f1 = fmaf(m.y, fast_tanh(s1), f1);
    }

    // ---- icd: 32 features for this wave ----
    const int m0 = wave * 32;
#pragma unroll
    for (int i = 0; i < 32; ++i) {
        int n = m0 + i;
        float x = icd_x[(size_t)n * BATCH + b];
        float4 c = sIcd[n];
        f0 = fmaf(c.z, fast_tanh(c.x * x), f0);
        f1 = fmaf(c.w, fast_tanh(c.y * x), f1);
    }

    sPart[wave][lane] = make_float2(f0, f1);
    __syncthreads();

    // ---- cross-wave reduce + 2-class softmax, wave 0 only ----
    if (t < 64) {
        float2 p0 = sPart[0][t];
        float2 p1 = sPart[1][t];
        float2 p2 = sPart[2][t];
        float2 p3 = sPart[3][t];
        float a0 = p0.x + p1.x + p2.x + p3.x;
        float a1 = p0.y + p1.y + p2.y + p3.y;
        float d  = a0 - a1;
        float e0 = __expf(-d);
        float e1 = __expf(d);
        int bb = blockIdx.x * 64 + t;
        out[bb]         = __builtin_amdgcn_rcpf(1.0f + e0);
        out[BATCH + bb] = __builtin_amdgcn_rcpf(1.0f + e1);
    }
}

extern "C" void kernel_launch(void* const* d_in, const int* in_sizes, int n_in,
                              void* d_out, int out_size, void* d_ws, size_t ws_size,
                              hipStream_t stream) {
    const float* num_x = (const float*)d_in[0];
    const float* cat_x = (const float*)d_in[1];
    const float* icd_x = (const float*)d_in[2];
    const float* W     = (const float*)d_in[3];
    const float* M     = (const float*)d_in[4];
    float* out = (float*)d_out;

    dim3 block(256);
    dim3 grid(BATCH / 64);  // 2048 blocks = 8 blocks/CU
    phenotype_softmax_kernel<<<grid, block, 0, stream>>>(num_x, cat_x, icd_x, W, M, out);
}